// Round 4
// baseline (1083.520 us; speedup 1.0000x reference)
//
#include <hip/hip_runtime.h>
#include <hip/hip_bf16.h>

#define B_ 256
#define S_ 512
#define H_ 512
#define E_ 128
#define V_ 30000
#define RNNIN_ 641

using bf16x8 = __attribute__((ext_vector_type(8))) short;
using f32x4  = __attribute__((ext_vector_type(4))) float;

__device__ __forceinline__ short f2bf(float f) {
  unsigned int u = __float_as_uint(f);
  u += 0x7fffu + ((u >> 16) & 1u);
  return (short)(u >> 16);
}

__device__ __forceinline__ float fast_tanh(float x) {
  x = fminf(10.f, fmaxf(-10.f, x));
  float t = __expf(2.f * x);
  return (t - 1.f) / (t + 1.f);
}

__device__ __forceinline__ float sigmoidf(float x) {
  return 1.f / (1.f + __expf(-x));
}

__device__ __forceinline__ void gload_lds16(const void* g, void* l) {
  __builtin_amdgcn_global_load_lds(
      (const __attribute__((address_space(1))) void*)g,
      (__attribute__((address_space(3))) void*)l, 16, 0, 0);
}

// ---------------------------------------------------------------------------
// Shared fp32 tile-GEMM bodies (proven; used for the small matmuls).
// ---------------------------------------------------------------------------
__device__ void gemm_nn_dev(float (*As)[65], float (*Bs)[65],
    const float* __restrict__ A, const float* __restrict__ Bm,
    const float* __restrict__ bias, float* __restrict__ C,
    int M, int N, int K, int m0, int n0)
{
  const int tid = threadIdx.x;
  const int tx = tid & 15, ty = tid >> 4;
  float acc[4][4] = {};
  for (int k0 = 0; k0 < K; k0 += 16) {
    __syncthreads();
    #pragma unroll
    for (int i = 0; i < 4; i++) {
      int e = tid + i * 256;
      int m = e >> 4, k = e & 15;
      float v = 0.f;
      if (m0 + m < M && k0 + k < K) v = A[(size_t)(m0 + m) * K + k0 + k];
      As[k][m] = v;
    }
    #pragma unroll
    for (int i = 0; i < 4; i++) {
      int e = tid + i * 256;
      int k = e >> 6, n = e & 63;
      float v = 0.f;
      if (n0 + n < N && k0 + k < K) v = Bm[(size_t)(k0 + k) * N + n0 + n];
      Bs[k][n] = v;
    }
    __syncthreads();
    #pragma unroll
    for (int k = 0; k < 16; k++) {
      float a[4], b[4];
      #pragma unroll
      for (int i = 0; i < 4; i++) a[i] = As[k][ty * 4 + i];
      #pragma unroll
      for (int j = 0; j < 4; j++) b[j] = Bs[k][tx * 4 + j];
      #pragma unroll
      for (int i = 0; i < 4; i++)
        #pragma unroll
        for (int j = 0; j < 4; j++) acc[i][j] += a[i] * b[j];
    }
  }
  #pragma unroll
  for (int i = 0; i < 4; i++) {
    int m = m0 + ty * 4 + i;
    if (m >= M) continue;
    #pragma unroll
    for (int j = 0; j < 4; j++) {
      int n = n0 + tx * 4 + j;
      if (n >= N) continue;
      C[(size_t)m * N + n] = acc[i][j] + bias[n];
    }
  }
}

__device__ void gemm_bt_dev(float (*As)[65], float (*Bs)[65],
    const float* __restrict__ A, const float* __restrict__ Bm,
    const float* __restrict__ bias, float* __restrict__ C,
    int M, int N, int K)
{
  const int m0 = blockIdx.x * 64, n0 = blockIdx.y * 64;
  const int tid = threadIdx.x;
  const int tx = tid & 15, ty = tid >> 4;
  float acc[4][4] = {};
  for (int k0 = 0; k0 < K; k0 += 16) {
    __syncthreads();
    #pragma unroll
    for (int i = 0; i < 4; i++) {
      int e = tid + i * 256;
      int m = e >> 4, k = e & 15;
      float v = 0.f;
      if (m0 + m < M && k0 + k < K) v = A[(size_t)(m0 + m) * K + k0 + k];
      As[k][m] = v;
    }
    #pragma unroll
    for (int i = 0; i < 4; i++) {
      int e = tid + i * 256;
      int n = e >> 4, k = e & 15;
      float v = 0.f;
      if (n0 + n < N && k0 + k < K) v = Bm[(size_t)(n0 + n) * K + k0 + k];
      Bs[k][n] = v;
    }
    __syncthreads();
    #pragma unroll
    for (int k = 0; k < 16; k++) {
      float a[4], b[4];
      #pragma unroll
      for (int i = 0; i < 4; i++) a[i] = As[k][ty * 4 + i];
      #pragma unroll
      for (int j = 0; j < 4; j++) b[j] = Bs[k][tx * 4 + j];
      #pragma unroll
      for (int i = 0; i < 4; i++)
        #pragma unroll
        for (int j = 0; j < 4; j++) acc[i][j] += a[i] * b[j];
    }
  }
  #pragma unroll
  for (int i = 0; i < 4; i++) {
    int m = m0 + ty * 4 + i;
    if (m >= M) continue;
    #pragma unroll
    for (int j = 0; j < 4; j++) {
      int n = n0 + tx * 4 + j;
      if (n >= N) continue;
      C[(size_t)m * N + n] = acc[i][j] + bias[n];
    }
  }
}

// ---------------------------------------------------------------------------
// prep: blocks [0,1024) pack attn_w[H:] into MFMA-fragment order (bf16);
//       blocks [1024,1056) compute hid_pb = h0 @ attn_w[:H] + attn_b.
// Fragment (kc32 = k>>5, nf = n>>4) is 1 KB contiguous at Btf +
// (kc32*32+nf)*512 shorts; within: slot = ((k>>3)&3)*16 + (n&15), elem k&7.
// ---------------------------------------------------------------------------
__global__ __launch_bounds__(256) void prep_fused(
    const float* __restrict__ attn_w, unsigned short* __restrict__ Btf,
    const float* __restrict__ hidden, const float* __restrict__ attn_b,
    float* __restrict__ hid_pb)
{
  __shared__ float As[16][65];
  __shared__ float Bs[16][65];
  int bid = blockIdx.x;
  if (bid < 1024) {
    int i = bid * 256 + threadIdx.x;   // 262144 elements of attn_w[H:]
    int k = i >> 9, n = i & 511;
    float v = attn_w[(size_t)H_ * H_ + i];
    int idx = ((((k >> 5) * 32 + (n >> 4)) * 4 + ((k >> 3) & 3)) * 16 + (n & 15)) * 8 + (k & 7);
    Btf[idx] = (unsigned short)f2bf(v);
  } else {
    int bb = bid - 1024;
    gemm_nn_dev(As, Bs, hidden, attn_w, attn_b, hid_pb, B_, H_, H_,
                (bb & 3) * 64, (bb >> 2) * 64);
  }
}

// ---------------------------------------------------------------------------
// Attention GEMM fused with tanh(.)·v_w reduction into scores.  v4:
// persistent-B. Each block owns an n-QUARTER (128 cols): B-slice (512k x
// 128n bf16 = 128 KB) lives in LDS for the whole block, loaded ONCE via
// global_load_lds. A (enc) is a pure prefetched stream: BK=32, depth-4
// register prefetch (4 named sets) kept in flight across raw barriers
// (lgkm-only fences). Block = 512 thr / 8 waves (2m x 4n), tile 128m x 128n,
// 4 m-tiles per block. Grid 1024 = 256 m-groups x 4 quarters; bid map puts
// the 4 quarter-blocks of one m-group on ONE XCD, co-resident -> A re-reads
// hit L2/L3, HBM sees enc ~once (268 MB floor).
// ---------------------------------------------------------------------------
__global__ __launch_bounds__(512) void attn_gemm_score(
    const float* __restrict__ A, const unsigned short* __restrict__ Btf,
    const float* __restrict__ hid_pb, const float* __restrict__ v_w,
    float* __restrict__ scores)
{
  __shared__ short Bs[65536];   // 128 KB: frag-major [kc16][f8][lane64][8]
  __shared__ short Abuf[8192];  // 16 KB: 2 x (8 KB: [mf8][slot64][8])

  // bid -> (w, q, mg): xcd = bid%8 fixed per mg; 4 q-blocks of an mg are
  // within 32 bids of each other -> co-resident on the same XCD.
  const int bid = blockIdx.x;
  const int w   = bid >> 8;
  const int i8  = bid & 255;
  const int q   = (i8 >> 3) & 3;
  const int mg  = w * 64 + (i8 >> 5) * 8 + (i8 & 7);
  const int nq0 = q * 128;

  const int tid  = threadIdx.x;
  const int lane = tid & 63;
  const int wv   = tid >> 6;
  const int wr   = wv >> 2;          // 0..1 : m-half
  const int wc   = wv & 3;           // 0..3 : n-slice (32 cols)
  const int quad = lane >> 4, l15 = lane & 15;

  // ---- B-slice -> LDS (once). 128 frags, 16 per wave, 1 KB each. ----
  #pragma unroll
  for (int i = 0; i < 16; i++) {
    int frag = wv * 16 + i;
    const unsigned short* g = Btf
        + ((size_t)((frag >> 3) * 32 + q * 8 + (frag & 7)) << 9) + lane * 8;
    gload_lds16((const void*)g, (void*)(Bs + (size_t)frag * 512));
  }

  // ---- A staging decode: thread -> (row rt, 8-float k-seg qs) ----
  const int rt = tid >> 2, qs = tid & 3;
  const float* tb = A + ((size_t)mg * 512 + rt) * H_ + qs * 8;
  short* awp = Abuf + (((rt >> 4) * 64) + qs * 16 + (rt & 15)) * 8;

  const float vw0 = v_w[nq0 + wc * 32 + l15];
  const float vw1 = v_w[nq0 + wc * 32 + 16 + l15];

  // depth-4 prefetch sets (tile 0, kt 0..3)
  float4 s0a = *(const float4*)(tb);
  float4 s0b = *(const float4*)(tb + 4);
  float4 s1a = *(const float4*)(tb + 32);
  float4 s1b = *(const float4*)(tb + 36);
  float4 s2a = *(const float4*)(tb + 64);
  float4 s2b = *(const float4*)(tb + 68);
  float4 s3a = *(const float4*)(tb + 96);
  float4 s3b = *(const float4*)(tb + 100);

  // B-slice (and the prologue A loads) must be in LDS before kt0.
  asm volatile("s_waitcnt vmcnt(0)" ::: "memory");
  __builtin_amdgcn_s_barrier();

  f32x4 acc[4][2];
  #pragma unroll
  for (int mi = 0; mi < 4; mi++) {
    acc[mi][0] = f32x4{0.f, 0.f, 0.f, 0.f};
    acc[mi][1] = f32x4{0.f, 0.f, 0.f, 0.f};
  }

#define KT_STEP(kt, SA, SB)                                                   \
  do {                                                                        \
    { bf16x8 f;                                                               \
      f[0] = f2bf(SA.x); f[1] = f2bf(SA.y); f[2] = f2bf(SA.z); f[3] = f2bf(SA.w); \
      f[4] = f2bf(SB.x); f[5] = f2bf(SB.y); f[6] = f2bf(SB.z); f[7] = f2bf(SB.w); \
      *(bf16x8*)(awp + ((kt) & 1) * 4096) = f; }                              \
    if ((kt) < 12) {                                                          \
      SA = *(const float4*)(tba + ((kt) + 4) * 32);                           \
      SB = *(const float4*)(tba + ((kt) + 4) * 32 + 4);                       \
    } else if (t < 3) {                                                       \
      SA = *(const float4*)(tba + 65536 + ((kt) - 12) * 32);                  \
      SB = *(const float4*)(tba + 65536 + ((kt) - 12) * 32 + 4);              \
    }                                                                         \
    asm volatile("s_waitcnt lgkmcnt(0)" ::: "memory");                        \
    __builtin_amdgcn_s_barrier();                                             \
    __builtin_amdgcn_sched_barrier(0);                                        \
    { const short* ap = Abuf + ((kt) & 1) * 4096 + wr * 2048 + lane * 8;      \
      bf16x8 a0 = *(const bf16x8*)(ap);                                       \
      bf16x8 a1 = *(const bf16x8*)(ap + 512);                                 \
      bf16x8 a2 = *(const bf16x8*)(ap + 1024);                                \
      bf16x8 a3 = *(const bf16x8*)(ap + 1536);                                \
      const short* bp = Bs + ((kt) * 8 + wc * 2) * 512 + lane * 8;            \
      bf16x8 b0 = *(const bf16x8*)(bp);                                       \
      bf16x8 b1 = *(const bf16x8*)(bp + 512);                                 \
      acc[0][0] = __builtin_amdgcn_mfma_f32_16x16x32_bf16(a0, b0, acc[0][0], 0, 0, 0); \
      acc[0][1] = __builtin_amdgcn_mfma_f32_16x16x32_bf16(a0, b1, acc[0][1], 0, 0, 0); \
      acc[1][0] = __builtin_amdgcn_mfma_f32_16x16x32_bf16(a1, b0, acc[1][0], 0, 0, 0); \
      acc[1][1] = __builtin_amdgcn_mfma_f32_16x16x32_bf16(a1, b1, acc[1][1], 0, 0, 0); \
      acc[2][0] = __builtin_amdgcn_mfma_f32_16x16x32_bf16(a2, b0, acc[2][0], 0, 0, 0); \
      acc[2][1] = __builtin_amdgcn_mfma_f32_16x16x32_bf16(a2, b1, acc[2][1], 0, 0, 0); \
      acc[3][0] = __builtin_amdgcn_mfma_f32_16x16x32_bf16(a3, b0, acc[3][0], 0, 0, 0); \
      acc[3][1] = __builtin_amdgcn_mfma_f32_16x16x32_bf16(a3, b1, acc[3][1], 0, 0, 0); \
    }                                                                         \
  } while (0)

  for (int t = 0; t < 4; t++) {
    const float* tba = tb + (size_t)t * 65536;   // 128 rows * 512 cols
    const int m0 = mg * 512 + t * 128;

    KT_STEP(0,  s0a, s0b);  KT_STEP(1,  s1a, s1b);
    KT_STEP(2,  s2a, s2b);  KT_STEP(3,  s3a, s3b);
    KT_STEP(4,  s0a, s0b);  KT_STEP(5,  s1a, s1b);
    KT_STEP(6,  s2a, s2b);  KT_STEP(7,  s3a, s3b);
    KT_STEP(8,  s0a, s0b);  KT_STEP(9,  s1a, s1b);
    KT_STEP(10, s2a, s2b);  KT_STEP(11, s3a, s3b);
    KT_STEP(12, s0a, s0b);  KT_STEP(13, s1a, s1b);
    KT_STEP(14, s2a, s2b);  KT_STEP(15, s3a, s3b);

    // ---- epilogue for this m-tile: tanh(acc + hid_pb)·v_w, 16-lane
    // reduce, cross-wave combine in LDS (buf0 is free), 1 atomic/row. ----
    float* part = (float*)Abuf;   // [128 rows][4 wc]
    #pragma unroll
    for (int mi = 0; mi < 4; mi++) {
      #pragma unroll
      for (int r = 0; r < 4; r++) {
        int row16 = mi * 16 + quad * 4 + r;
        int m = m0 + wr * 64 + row16;
        int b = m & (B_ - 1);
        int n0l = nq0 + wc * 32 + l15;
        float e0 = acc[mi][0][r] + hid_pb[b * H_ + n0l];
        float e1 = acc[mi][1][r] + hid_pb[b * H_ + n0l + 16];
        float sum = fast_tanh(e0) * vw0 + fast_tanh(e1) * vw1;
        sum += __shfl_xor(sum, 1);
        sum += __shfl_xor(sum, 2);
        sum += __shfl_xor(sum, 4);
        sum += __shfl_xor(sum, 8);
        if (l15 == 0) part[(wr * 64 + row16) * 4 + wc] = sum;
      }
    }
    asm volatile("s_waitcnt lgkmcnt(0)" ::: "memory");
    __builtin_amdgcn_s_barrier();
    __builtin_amdgcn_sched_barrier(0);
    if (tid < 128) {
      float s4 = part[tid * 4 + 0] + part[tid * 4 + 1]
               + part[tid * 4 + 2] + part[tid * 4 + 3];
      int m = m0 + tid;
      atomicAdd(scores + (m & (B_ - 1)) * S_ + (m >> 8), s4);
    }
    asm volatile("s_waitcnt lgkmcnt(0)" ::: "memory");
    __builtin_amdgcn_s_barrier();
    __builtin_amdgcn_sched_barrier(0);

    #pragma unroll
    for (int mi = 0; mi < 4; mi++) {
      acc[mi][0] = f32x4{0.f, 0.f, 0.f, 0.f};
      acc[mi][1] = f32x4{0.f, 0.f, 0.f, 0.f};
    }
  }
#undef KT_STEP
}

// ---------------------------------------------------------------------------
// GRU input/hidden GEMMs share one launch (z-dim).
// ---------------------------------------------------------------------------
__global__ __launch_bounds__(256) void gemm_gru(
    const float* __restrict__ xb, const float* __restrict__ w_ih,
    const float* __restrict__ b_ih, float* __restrict__ gi,
    const float* __restrict__ hid, const float* __restrict__ w_hh,
    const float* __restrict__ b_hh, float* __restrict__ gh)
{
  __shared__ float As[16][65];
  __shared__ float Bs[16][65];
  if (blockIdx.z == 0) gemm_bt_dev(As, Bs, xb, w_ih, b_ih, gi, B_, 1536, RNNIN_);
  else                 gemm_bt_dev(As, Bs, hid, w_hh, b_hh, gh, B_, 1536, H_);
}

// ---------------------------------------------------------------------------
// Logits GEMM: C(256,30000) = h1 @ fc_id_w + b.  (unchanged)
// ---------------------------------------------------------------------------
__global__ __launch_bounds__(256, 4) void logits_gemm(
    const unsigned short* __restrict__ Ab, const float* __restrict__ Bw,
    const float* __restrict__ bias, float* __restrict__ C)
{
  __shared__ short As[2 * 16 * 64 * 8];   // [c][mt][lane][8] = 32 KB
  __shared__ short Bs[2 * 4 * 64 * 8];    // [c][tj][lane][8] = 8 KB
  const int n0 = blockIdx.x * 64;
  const int tid = threadIdx.x;
  const int lane = tid & 63;
  const int wv = tid >> 6;
  const int quad = lane >> 4, l15 = lane & 15;

  f32x4 acc[4][4];
  #pragma unroll
  for (int i = 0; i < 4; i++)
    #pragma unroll
    for (int j = 0; j < 4; j++) acc[i][j] = f32x4{0.f, 0.f, 0.f, 0.f};

  const int nB  = tid & 63;
  const int kg  = tid >> 6;
  const int cB  = kg >> 1;
  const int q0  = (kg & 1) * 2;
  const int tjB = nB >> 4;
  const bool nOK = (n0 + nB) < V_;

  for (int kt = 0; kt < 8; kt++) {
    const int kb = kt * 64;
    __syncthreads();
    #pragma unroll
    for (int p = 0; p < 8; p++) {
      int m = p * 32 + (tid >> 3), f = tid & 7;
      int c = f >> 2, qq = f & 3;
      bf16x8 v = *(const bf16x8*)(Ab + (size_t)m * H_ + kb + c * 32 + qq * 8);
      int mt = m >> 4, ld = qq * 16 + (m & 15);
      *(bf16x8*)&As[((c * 16 + mt) * 64 + ld) * 8] = v;
    }
    {
      float col[16];
      const float* src = Bw + (size_t)(kb + kg * 16) * V_ + n0 + nB;
      #pragma unroll
      for (int i = 0; i < 16; i++) col[i] = nOK ? src[(size_t)i * V_] : 0.f;
      bf16x8 f0, f1;
      #pragma unroll
      for (int i = 0; i < 8; i++) { f0[i] = f2bf(col[i]); f1[i] = f2bf(col[8 + i]); }
      int ld0 = q0 * 16 + (nB & 15);
      *(bf16x8*)&Bs[((cB * 4 + tjB) * 64 + ld0) * 8] = f0;
      *(bf16x8*)&Bs[((cB * 4 + tjB) * 64 + ld0 + 16) * 8] = f1;
    }
    __syncthreads();
    #pragma unroll
    for (int c = 0; c < 2; c++) {
      bf16x8 a[4], b[4];
      #pragma unroll
      for (int ti = 0; ti < 4; ti++)
        a[ti] = *(const bf16x8*)&As[((c * 16 + wv * 4 + ti) * 64 + lane) * 8];
      #pragma unroll
      for (int tj = 0; tj < 4; tj++)
        b[tj] = *(const bf16x8*)&Bs[((c * 4 + tj) * 64 + lane) * 8];
      #pragma unroll
      for (int ti = 0; ti < 4; ti++)
        #pragma unroll
        for (int tj = 0; tj < 4; tj++)
          acc[ti][tj] = __builtin_amdgcn_mfma_f32_16x16x32_bf16(a[ti], b[tj], acc[ti][tj], 0, 0, 0);
    }
  }
  #pragma unroll
  for (int ti = 0; ti < 4; ti++)
    #pragma unroll
    for (int r = 0; r < 4; r++) {
      int m = wv * 64 + ti * 16 + quad * 4 + r;
      #pragma unroll
      for (int tj = 0; tj < 4; tj++) {
        int n = n0 + tj * 16 + l15;
        if (n < V_) C[(size_t)m * V_ + n] = acc[ti][tj][r] + bias[n];
      }
    }
}

// --------------------------- small kernels ---------------------------------
__global__ __launch_bounds__(256) void attn_softmax(
    const float* __restrict__ scores, const int* __restrict__ mask, float* __restrict__ aw)
{
  int b = blockIdx.x, tid = threadIdx.x;
  __shared__ float red[256];
  float v0 = scores[b * S_ + tid];
  float v1 = scores[b * S_ + tid + 256];
  if (mask[b * S_ + tid] == 0) v0 = -1e10f;
  if (mask[b * S_ + tid + 256] == 0) v1 = -1e10f;
  red[tid] = fmaxf(v0, v1);
  __syncthreads();
  for (int off = 128; off; off >>= 1) { if (tid < off) red[tid] = fmaxf(red[tid], red[tid + off]); __syncthreads(); }
  float mx = red[0];
  __syncthreads();
  float e0 = __expf(v0 - mx), e1 = __expf(v1 - mx);
  red[tid] = e0 + e1;
  __syncthreads();
  for (int off = 128; off; off >>= 1) { if (tid < off) red[tid] += red[tid + off]; __syncthreads(); }
  float inv = 1.f / red[0];
  aw[b * S_ + tid] = e0 * inv;
  aw[b * S_ + tid + 256] = e1 * inv;
}

// S split into 8 chunks -> 2048 blocks; deterministic partials into wpart.
__global__ __launch_bounds__(512) void attn_weighted_part(
    const float* __restrict__ aw, const float* __restrict__ enc, float* __restrict__ wpart)
{
  int b = blockIdx.x, c = blockIdx.y, h = threadIdx.x;
  __shared__ float a_s[64];
  if (h < 64) a_s[h] = aw[b * S_ + c * 64 + h];
  __syncthreads();
  const float* ep = enc + ((size_t)(c * 64) * B_ + b) * H_ + h;
  float acc = 0.f;
  #pragma unroll 8
  for (int s = 0; s < 64; s++)
    acc += a_s[s] * ep[(size_t)s * B_ * H_];
  wpart[((size_t)c * B_ + b) * H_ + h] = acc;
}

__global__ void build_x(const float* __restrict__ wpart, const int* __restrict__ ids,
                        const float* __restrict__ emb, const float* __restrict__ rate,
                        float* __restrict__ x)
{
  int i = blockIdx.x * 256 + threadIdx.x;
  if (i >= B_ * RNNIN_) return;
  int b = i / RNNIN_, j = i % RNNIN_;
  float v;
  if (j < H_) {
    size_t o = (size_t)b * H_ + j;
    const size_t st = (size_t)B_ * H_;
    v = 0.f;
    #pragma unroll
    for (int c = 0; c < 8; c++) v += wpart[o + c * st];
  }
  else if (j < H_ + E_) v = emb[(size_t)ids[b] * E_ + (j - H_)];
  else v = rate[b];
  x[i] = v;
}

__global__ void gru_gates(const float* __restrict__ gi, const float* __restrict__ gh,
                          const float* __restrict__ h0, float* __restrict__ h1,
                          unsigned short* __restrict__ h1b, float* __restrict__ h1_out)
{
  int i = blockIdx.x * 256 + threadIdx.x;  // B*H
  int b = i >> 9, j = i & (H_ - 1);
  const float* gib = gi + (size_t)b * 1536;
  const float* ghb = gh + (size_t)b * 1536;
  float r = sigmoidf(gib[j] + ghb[j]);
  float z = sigmoidf(gib[512 + j] + ghb[512 + j]);
  float n = fast_tanh(gib[1024 + j] + r * ghb[1024 + j]);
  float h = (1.f - z) * n + z * h0[i];
  h1[i] = h;
  h1b[i] = (unsigned short)f2bf(h);
  h1_out[i] = h;
}

__global__ __launch_bounds__(1024) void softmax_fused(
    float* __restrict__ lp, const float* __restrict__ cv, int* __restrict__ maxid)
{
  int b = blockIdx.x, tid = threadIdx.x;
  int wid = tid >> 6, lane = tid & 63;
  float* row = lp + (size_t)b * V_;
  const float* cvr = cv + (size_t)b * V_;
  __shared__ float redf[16];
  __shared__ float rede[16];
  __shared__ int   redi[16];

  float mx = -INFINITY;
  for (int v = tid; v < V_; v += 1024) mx = fmaxf(mx, row[v]);
  #pragma unroll
  for (int o = 1; o < 64; o <<= 1) mx = fmaxf(mx, __shfl_xor(mx, o));
  if (lane == 0) redf[wid] = mx;
  __syncthreads();
  if (tid == 0) {
    float m = redf[0];
    for (int i = 1; i < 16; i++) m = fmaxf(m, redf[i]);
    redf[0] = m;
  }
  __syncthreads();
  float M = redf[0];
  __syncthreads();

  float s = 0.f, best = -1.f;
  int bi = 0;
  for (int v = tid; v < V_; v += 1024) {
    float e = __expf(row[v] - M) * cvr[v];
    row[v] = e;
    s += e;
    if (e > best) { best = e; bi = v; }
  }
  #pragma unroll
  for (int o = 1; o < 64; o <<= 1) {
    s += __shfl_xor(s, o);
    float ob = __shfl_xor(best, o);
    int oi = __shfl_xor(bi, o);
    if (ob > best || (ob == best && oi < bi)) { best = ob; bi = oi; }
  }
  if (lane == 0) { redf[wid] = s; rede[wid] = best; redi[wid] = bi; }
  __syncthreads();
  if (tid == 0) {
    float ss = 0.f, bb = rede[0];
    int ii = redi[0];
    for (int i = 0; i < 16; i++) {
      ss += redf[i];
      if (rede[i] > bb || (rede[i] == bb && redi[i] < ii)) { bb = rede[i]; ii = redi[i]; }
    }
    redf[0] = ss;
    maxid[b] = ii;
  }
  __syncthreads();
  float inv = 1.f / redf[0];
  for (int v = tid; v < V_; v += 1024) {
    float p = row[v] * inv;
    p = fminf(fmaxf(p, 1e-6f), 1.f);
    row[v] = __logf(p);
  }
}

// Tandem GEMM with fused A-gather ([emb[maxid], h1]) and relu.
__global__ __launch_bounds__(256) void tandem_gemm(
    const int* __restrict__ maxid, const float* __restrict__ emb,
    const float* __restrict__ h1, const float* __restrict__ tan_w,
    const float* __restrict__ tan_b, float* __restrict__ rate_in)
{
  __shared__ float As[16][65];
  __shared__ float Bs[16][65];
  const int m0 = blockIdx.x * 64, n0 = blockIdx.y * 64;
  const int tid = threadIdx.x;
  const int tx = tid & 15, ty = tid >> 4;
  float acc[4][4] = {};
  for (int k0 = 0; k0 < 640; k0 += 16) {
    __syncthreads();
    #pragma unroll
    for (int i = 0; i < 4; i++) {
      int e = tid + i * 256;
      int m = e >> 4, kk = e & 15;
      int mm = m0 + m, k = k0 + kk;
      float v = (k < E_) ? emb[(size_t)maxid[mm] * E_ + k]
                         : h1[(size_t)mm * H_ + (k - E_)];
      As[kk][m] = v;
    }
    #pragma unroll
    for (int i = 0; i < 4; i++) {
      int e = tid + i * 256;
      int k = e >> 6, n = e & 63;
      Bs[k][n] = tan_w[(size_t)(k0 + k) * H_ + n0 + n];
    }
    __syncthreads();
    #pragma unroll
    for (int k = 0; k < 16; k++) {
      float a[4], b[4];
      #pragma unroll
      for (int i = 0; i < 4; i++) a[i] = As[k][ty * 4 + i];
      #pragma unroll
      for (int j = 0; j < 4; j++) b[j] = Bs[k][tx * 4 + j];
      #pragma unroll
      for (int i = 0; i < 4; i++)
        #pragma unroll
        for (int j = 0; j < 4; j++) acc[i][j] += a[i] * b[j];
    }
  }
  #pragma unroll
  for (int i = 0; i < 4; i++) {
    int m = m0 + ty * 4 + i;
    #pragma unroll
    for (int j = 0; j < 4; j++) {
      int n = n0 + tx * 4 + j;
      rate_in[(size_t)m * H_ + n] = fmaxf(acc[i][j] + tan_b[n], 0.f);
    }
  }
}

__global__ __launch_bounds__(64) void rate_head(const float* __restrict__ rate_in,
                                                const float* __restrict__ rate_w,
                                                const float* __restrict__ rate_b,
                                                float* __restrict__ out)
{
  int b = blockIdx.x, t = threadIdx.x;
  float s = 0.f;
  #pragma unroll
  for (int i = 0; i < 8; i++) s += rate_in[b * H_ + t + 64 * i] * rate_w[t + 64 * i];
  #pragma unroll
  for (int m = 32; m; m >>= 1) s += __shfl_xor(s, m);
  if (t == 0) out[b] = sigmoidf(s + rate_b[0]);
}

// ---------------------------------------------------------------------------
extern "C" void kernel_launch(void* const* d_in, const int* in_sizes, int n_in,
                              void* d_out, int out_size, void* d_ws, size_t ws_size,
                              hipStream_t stream)
{
  const int*   input_id   = (const int*)  d_in[0];
  const float* input_rate = (const float*)d_in[1];
  const float* hidden     = (const float*)d_in[2];
  const float* enc        = (const float*)d_in[3];
  const int*   attn_mask  = (const int*)  d_in[4];
  const float* cv         = (const float*)d_in[5];
  const float* emb        = (const float*)d_in[6];
  const float* attn_w     = (const float*)d_in[7];
  const float* attn_b     = (const float*)d_in[8];
  const float* v_w        = (const float*)d_in[9];
  const float* w_ih       = (const float*)d_in[10];
  const float* w_hh       = (const float*)d_in[11];
  const float* b_ih       = (const float*)d_in[12];
  const float* b_hh       = (const float*)d_in[13];
  const float* fc_w       = (const float*)d_in[14];
  const float* fc_b       = (const float*)d_in[15];
  const float* tan_w      = (const float*)d_in[16];
  const float* tan_b      = (const float*)d_in[17];
  const float* rate_w     = (const float*)d_in[18];
  const float* rate_b     = (const float*)d_in[19];

  float* out = (float*)d_out;
  float* ws  = (float*)d_ws;
  float* hid_pb   = ws;                   // [0,       131072)
  float* scores   = ws + 131072;          // [131072,  262144)
  float* aw       = ws + 262144;          // [262144,  393216)
  float* xbuf     = ws + 524288;          // [524288,  688384)  B*641
  float* gi       = ws + 688384;          // [688384, 1081600)  B*1536
  float* gh       = ws + 1081600;         // [1081600,1474816)  B*1536
  float* h1       = ws + 1474816;         // [1474816,1605888)  B*H
  float* rate_in  = ws + 1605888;         // [1605888,1736960)  B*H
  int*   maxid    = (int*)(ws + 1736960); // [1736960,1737216)  B ints
  unsigned short* Btf = (unsigned short*)(ws + 1737216); // 512KB packed B
  unsigned short* h1b = (unsigned short*)(ws + 1868288); // 256*512 bf16
  // wpart: 8*B*H floats overlays [gi .. rate_in end); consumed by build_x
  // BEFORE gemm_gru/gru_gates/tandem write that region.
  float* wpart = gi;

  float* out_pred = out;
  float* out_rate = out + (size_t)B_ * V_;
  float* out_h1   = out + (size_t)B_ * V_ + B_;

  hipMemsetAsync(scores, 0, (size_t)B_ * S_ * sizeof(float), stream);

  prep_fused<<<1056, 256, 0, stream>>>(attn_w, Btf, hidden, attn_b, hid_pb);

  attn_gemm_score<<<1024, 512, 0, stream>>>(enc, Btf, hid_pb, v_w, scores);

  attn_softmax<<<B_, 256, 0, stream>>>(scores, attn_mask, aw);
  attn_weighted_part<<<dim3(B_, 8), 512, 0, stream>>>(aw, enc, wpart);
  build_x<<<641, 256, 0, stream>>>(wpart, input_id, emb, input_rate, xbuf);

  gemm_gru<<<dim3(4, 24, 2), 256, 0, stream>>>(xbuf, w_ih, b_ih, gi, hidden, w_hh, b_hh, gh);
  gru_gates<<<512, 256, 0, stream>>>(gi, gh, hidden, h1, h1b, out_h1);

  logits_gemm<<<469, 256, 0, stream>>>(h1b, fc_w, fc_b, out_pred);
  softmax_fused<<<B_, 1024, 0, stream>>>(out_pred, cv, maxid);

  tandem_gemm<<<dim3(4, 8), 256, 0, stream>>>(maxid, emb, h1, tan_w, tan_b, rate_in);
  rate_head<<<B_, 64, 0, stream>>>(rate_in, rate_w, rate_b, out_rate);
}

// Round 5
// 981.773 us; speedup vs baseline: 1.1036x; 1.1036x over previous
//
#include <hip/hip_runtime.h>
#include <hip/hip_bf16.h>

#define B_ 256
#define S_ 512
#define H_ 512
#define E_ 128
#define V_ 30000
#define RNNIN_ 641

using bf16x8 = __attribute__((ext_vector_type(8))) short;
using f32x4  = __attribute__((ext_vector_type(4))) float;

__device__ __forceinline__ short f2bf(float f) {
  unsigned int u = __float_as_uint(f);
  u += 0x7fffu + ((u >> 16) & 1u);
  return (short)(u >> 16);
}

// 2 x f32 -> packed bf16 (RNE), single VALU instruction on gfx950.
__device__ __forceinline__ unsigned cvtpk(float a, float b) {
  unsigned r;
  asm("v_cvt_pk_bf16_f32 %0, %1, %2" : "=v"(r) : "v"(a), "v"(b));
  return r;
}

// tanh(x) = 1 - 2/(1+e^{2x}) : no clamp needed (e^inf -> 1-0, e^0 -> -1),
// 5 VALU/trans insts vs 9 for the (t-1)/(t+1) form.
__device__ __forceinline__ float fast_tanh(float x) {
  float t = __expf(2.f * x);
  return 1.f - 2.f / (t + 1.f);
}

__device__ __forceinline__ float sigmoidf(float x) {
  return 1.f / (1.f + __expf(-x));
}

// ---------------------------------------------------------------------------
// Shared fp32 tile-GEMM bodies (proven; used for the small matmuls).
// ---------------------------------------------------------------------------
__device__ void gemm_nn_dev(float (*As)[65], float (*Bs)[65],
    const float* __restrict__ A, const float* __restrict__ Bm,
    const float* __restrict__ bias, float* __restrict__ C,
    int M, int N, int K, int m0, int n0)
{
  const int tid = threadIdx.x;
  const int tx = tid & 15, ty = tid >> 4;
  float acc[4][4] = {};
  for (int k0 = 0; k0 < K; k0 += 16) {
    __syncthreads();
    #pragma unroll
    for (int i = 0; i < 4; i++) {
      int e = tid + i * 256;
      int m = e >> 4, k = e & 15;
      float v = 0.f;
      if (m0 + m < M && k0 + k < K) v = A[(size_t)(m0 + m) * K + k0 + k];
      As[k][m] = v;
    }
    #pragma unroll
    for (int i = 0; i < 4; i++) {
      int e = tid + i * 256;
      int k = e >> 6, n = e & 63;
      float v = 0.f;
      if (n0 + n < N && k0 + k < K) v = Bm[(size_t)(k0 + k) * N + n0 + n];
      Bs[k][n] = v;
    }
    __syncthreads();
    #pragma unroll
    for (int k = 0; k < 16; k++) {
      float a[4], b[4];
      #pragma unroll
      for (int i = 0; i < 4; i++) a[i] = As[k][ty * 4 + i];
      #pragma unroll
      for (int j = 0; j < 4; j++) b[j] = Bs[k][tx * 4 + j];
      #pragma unroll
      for (int i = 0; i < 4; i++)
        #pragma unroll
        for (int j = 0; j < 4; j++) acc[i][j] += a[i] * b[j];
    }
  }
  #pragma unroll
  for (int i = 0; i < 4; i++) {
    int m = m0 + ty * 4 + i;
    if (m >= M) continue;
    #pragma unroll
    for (int j = 0; j < 4; j++) {
      int n = n0 + tx * 4 + j;
      if (n >= N) continue;
      C[(size_t)m * N + n] = acc[i][j] + bias[n];
    }
  }
}

__device__ void gemm_bt_dev(float (*As)[65], float (*Bs)[65],
    const float* __restrict__ A, const float* __restrict__ Bm,
    const float* __restrict__ bias, float* __restrict__ C,
    int M, int N, int K)
{
  const int m0 = blockIdx.x * 64, n0 = blockIdx.y * 64;
  const int tid = threadIdx.x;
  const int tx = tid & 15, ty = tid >> 4;
  float acc[4][4] = {};
  for (int k0 = 0; k0 < K; k0 += 16) {
    __syncthreads();
    #pragma unroll
    for (int i = 0; i < 4; i++) {
      int e = tid + i * 256;
      int m = e >> 4, k = e & 15;
      float v = 0.f;
      if (m0 + m < M && k0 + k < K) v = A[(size_t)(m0 + m) * K + k0 + k];
      As[k][m] = v;
    }
    #pragma unroll
    for (int i = 0; i < 4; i++) {
      int e = tid + i * 256;
      int n = e >> 4, k = e & 15;
      float v = 0.f;
      if (n0 + n < N && k0 + k < K) v = Bm[(size_t)(n0 + n) * K + k0 + k];
      Bs[k][n] = v;
    }
    __syncthreads();
    #pragma unroll
    for (int k = 0; k < 16; k++) {
      float a[4], b[4];
      #pragma unroll
      for (int i = 0; i < 4; i++) a[i] = As[k][ty * 4 + i];
      #pragma unroll
      for (int j = 0; j < 4; j++) b[j] = Bs[k][tx * 4 + j];
      #pragma unroll
      for (int i = 0; i < 4; i++)
        #pragma unroll
        for (int j = 0; j < 4; j++) acc[i][j] += a[i] * b[j];
    }
  }
  #pragma unroll
  for (int i = 0; i < 4; i++) {
    int m = m0 + ty * 4 + i;
    if (m >= M) continue;
    #pragma unroll
    for (int j = 0; j < 4; j++) {
      int n = n0 + tx * 4 + j;
      if (n >= N) continue;
      C[(size_t)m * N + n] = acc[i][j] + bias[n];
    }
  }
}

// ---------------------------------------------------------------------------
// prep: blocks [0,1024) pack attn_w[H:] into MFMA-fragment order (bf16);
//       blocks [1024,1056) compute hid_pb = h0 @ attn_w[:H] + attn_b.
// Fragment (kc32 = k>>5, nf = n>>4) is 1 KB contiguous at Btf +
// (kc32*32+nf)*512 shorts; within: slot = ((k>>3)&3)*16 + (n&15), elem k&7.
// ---------------------------------------------------------------------------
__global__ __launch_bounds__(256) void prep_fused(
    const float* __restrict__ attn_w, unsigned short* __restrict__ Btf,
    const float* __restrict__ hidden, const float* __restrict__ attn_b,
    float* __restrict__ hid_pb)
{
  __shared__ float As[16][65];
  __shared__ float Bs[16][65];
  int bid = blockIdx.x;
  if (bid < 1024) {
    int i = bid * 256 + threadIdx.x;   // 262144 elements of attn_w[H:]
    int k = i >> 9, n = i & 511;
    float v = attn_w[(size_t)H_ * H_ + i];
    int idx = ((((k >> 5) * 32 + (n >> 4)) * 4 + ((k >> 3) & 3)) * 16 + (n & 15)) * 8 + (k & 7);
    Btf[idx] = (unsigned short)f2bf(v);
  } else {
    int bb = bid - 1024;
    gemm_nn_dev(As, Bs, hidden, attn_w, attn_b, hid_pb, B_, H_, H_,
                (bb & 3) * 64, (bb >> 2) * 64);
  }
}

// ---------------------------------------------------------------------------
// Attention GEMM fused with tanh(.)·v_w reduction into scores.  v5:
// full-N tile 64m x 512n, 512 thr / 8 n-waves, BK=64, 2048 blocks.
// - A (enc fp32) converted ONCE per panel via v_cvt_pk_bf16_f32 (1 inst /
//   2 elems -- the f2bf VALU tax was ~= the MFMA time in R1/R3).
// - B fragments straight from L2 into registers (packed Btf, no LDS).
// - depth-2 A register prefetch kept in flight across raw barriers
//   (lgkm-only fences; vmcnt waits inserted by compiler at uses).
// - full row per block -> scores stored directly: no atomics, no memset.
// ---------------------------------------------------------------------------
__global__ __launch_bounds__(512) void attn_gemm_score(
    const float* __restrict__ A, const unsigned short* __restrict__ Btf,
    const float* __restrict__ hid_pb, const float* __restrict__ v_w,
    float* __restrict__ scores)
{
  __shared__ short Abuf[2 * 4096];   // 16 KB: [buf][(kc*4+mi)*64 + slot][8]

  const int m0 = blockIdx.x * 64;
  const int tid  = threadIdx.x;
  const int lane = tid & 63;
  const int wv   = tid >> 6;            // 0..7 = n-wave (64 cols each)
  const int quad = lane >> 4, l15 = lane & 15;

  // A staging decode: thread -> (row rt 0..63, 8-float k-seg qs 0..7)
  const int rt = tid >> 3, qs = tid & 7;
  const float* aptr = A + ((size_t)(m0 + rt)) * H_ + qs * 8;
  const int kc = qs >> 2, qq = qs & 3;
  short* awp = Abuf + ((kc * 4 + (rt >> 4)) * 64 + qq * 16 + (rt & 15)) * 8;

  f32x4 acc[4][4];
  #pragma unroll
  for (int i = 0; i < 4; i++)
    #pragma unroll
    for (int j = 0; j < 4; j++) acc[i][j] = f32x4{0.f, 0.f, 0.f, 0.f};

  // depth-2 prefetch sets (kt 0 and 1)
  float4 p0a = *(const float4*)(aptr);
  float4 p0b = *(const float4*)(aptr + 4);
  float4 p1a = *(const float4*)(aptr + 64);
  float4 p1b = *(const float4*)(aptr + 68);

#define KT_STEP(kt, PA, PB)                                                   \
  do {                                                                        \
    /* B frags for this kt: per-lane dwordx4 from L2 (packed layout) */       \
    bf16x8 b[2][4];                                                           \
    _Pragma("unroll")                                                         \
    for (int kcc = 0; kcc < 2; kcc++)                                         \
      _Pragma("unroll")                                                       \
      for (int tj = 0; tj < 4; tj++)                                          \
        b[kcc][tj] = *(const bf16x8*)(Btf                                     \
            + ((((kt) * 2 + kcc) * 32 + wv * 4 + tj) << 9) + lane * 8);       \
    /* convert & write A(kt): 4 x cvt_pk + one b128 LDS write */              \
    { uint4 pk;                                                               \
      pk.x = cvtpk(PA.x, PA.y); pk.y = cvtpk(PA.z, PA.w);                     \
      pk.z = cvtpk(PB.x, PB.y); pk.w = cvtpk(PB.z, PB.w);                     \
      *(uint4*)(awp + ((kt) & 1) * 4096) = pk; }                              \
    /* prefetch A(kt+2): stays in flight across the barrier */                \
    if ((kt) < 6) {                                                           \
      PA = *(const float4*)(aptr + ((kt) + 2) * 64);                          \
      PB = *(const float4*)(aptr + ((kt) + 2) * 64 + 4);                      \
    }                                                                         \
    asm volatile("s_waitcnt lgkmcnt(0)" ::: "memory");                        \
    __builtin_amdgcn_s_barrier();                                             \
    __builtin_amdgcn_sched_barrier(0);                                        \
    { const short* ab = Abuf + ((kt) & 1) * 4096;                             \
      _Pragma("unroll")                                                       \
      for (int kcc = 0; kcc < 2; kcc++) {                                     \
        bf16x8 a[4];                                                          \
        _Pragma("unroll")                                                     \
        for (int mi = 0; mi < 4; mi++)                                        \
          a[mi] = *(const bf16x8*)&ab[((kcc * 4 + mi) * 64 + lane) * 8];      \
        _Pragma("unroll")                                                     \
        for (int mi = 0; mi < 4; mi++)                                        \
          _Pragma("unroll")                                                   \
          for (int tj = 0; tj < 4; tj++)                                      \
            acc[mi][tj] = __builtin_amdgcn_mfma_f32_16x16x32_bf16(            \
                a[mi], b[kcc][tj], acc[mi][tj], 0, 0, 0);                     \
      }                                                                       \
    }                                                                         \
  } while (0)

  KT_STEP(0, p0a, p0b);  KT_STEP(1, p1a, p1b);
  KT_STEP(2, p0a, p0b);  KT_STEP(3, p1a, p1b);
  KT_STEP(4, p0a, p0b);  KT_STEP(5, p1a, p1b);
  KT_STEP(6, p0a, p0b);  KT_STEP(7, p1a, p1b);
#undef KT_STEP

  // Epilogue: tanh(acc + hid_pb)·v_w over this wave's 64 cols, 16-lane
  // reduce, cross-wave combine (8 waves) in LDS, direct store (no atomics).
  const float vw0 = v_w[wv * 64 + l15];
  const float vw1 = v_w[wv * 64 + 16 + l15];
  const float vw2 = v_w[wv * 64 + 32 + l15];
  const float vw3 = v_w[wv * 64 + 48 + l15];

  float* part = (float*)Abuf;   // [64 rows][8 wv] = 2 KB (Abuf is free)
  #pragma unroll
  for (int mi = 0; mi < 4; mi++) {
    #pragma unroll
    for (int r = 0; r < 4; r++) {
      int row16 = mi * 16 + quad * 4 + r;
      int m = m0 + row16;
      int b = m & (B_ - 1);
      const float* hp = hid_pb + (size_t)b * H_ + wv * 64 + l15;
      float e0 = acc[mi][0][r] + hp[0];
      float e1 = acc[mi][1][r] + hp[16];
      float e2 = acc[mi][2][r] + hp[32];
      float e3 = acc[mi][3][r] + hp[48];
      float sum = fast_tanh(e0) * vw0 + fast_tanh(e1) * vw1
                + fast_tanh(e2) * vw2 + fast_tanh(e3) * vw3;
      sum += __shfl_xor(sum, 1);
      sum += __shfl_xor(sum, 2);
      sum += __shfl_xor(sum, 4);
      sum += __shfl_xor(sum, 8);
      if (l15 == 0) part[row16 * 8 + wv] = sum;
    }
  }
  asm volatile("s_waitcnt lgkmcnt(0)" ::: "memory");
  __builtin_amdgcn_s_barrier();
  __builtin_amdgcn_sched_barrier(0);
  if (tid < 64) {
    float s8 = 0.f;
    #pragma unroll
    for (int w = 0; w < 8; w++) s8 += part[tid * 8 + w];
    int m = m0 + tid;
    scores[(m & (B_ - 1)) * S_ + (m >> 8)] = s8;
  }
}

// ---------------------------------------------------------------------------
// GRU input/hidden GEMMs share one launch (z-dim).
// ---------------------------------------------------------------------------
__global__ __launch_bounds__(256) void gemm_gru(
    const float* __restrict__ xb, const float* __restrict__ w_ih,
    const float* __restrict__ b_ih, float* __restrict__ gi,
    const float* __restrict__ hid, const float* __restrict__ w_hh,
    const float* __restrict__ b_hh, float* __restrict__ gh)
{
  __shared__ float As[16][65];
  __shared__ float Bs[16][65];
  if (blockIdx.z == 0) gemm_bt_dev(As, Bs, xb, w_ih, b_ih, gi, B_, 1536, RNNIN_);
  else                 gemm_bt_dev(As, Bs, hid, w_hh, b_hh, gh, B_, 1536, H_);
}

// ---------------------------------------------------------------------------
// Logits GEMM: C(256,30000) = h1 @ fc_id_w + b.  (cvt_pk conversions)
// ---------------------------------------------------------------------------
__global__ __launch_bounds__(256, 4) void logits_gemm(
    const unsigned short* __restrict__ Ab, const float* __restrict__ Bw,
    const float* __restrict__ bias, float* __restrict__ C)
{
  __shared__ short As[2 * 16 * 64 * 8];   // [c][mt][lane][8] = 32 KB
  __shared__ short Bs[2 * 4 * 64 * 8];    // [c][tj][lane][8] = 8 KB
  const int n0 = blockIdx.x * 64;
  const int tid = threadIdx.x;
  const int lane = tid & 63;
  const int wv = tid >> 6;
  const int quad = lane >> 4, l15 = lane & 15;

  f32x4 acc[4][4];
  #pragma unroll
  for (int i = 0; i < 4; i++)
    #pragma unroll
    for (int j = 0; j < 4; j++) acc[i][j] = f32x4{0.f, 0.f, 0.f, 0.f};

  const int nB  = tid & 63;
  const int kg  = tid >> 6;
  const int cB  = kg >> 1;
  const int q0  = (kg & 1) * 2;
  const int tjB = nB >> 4;
  const bool nOK = (n0 + nB) < V_;

  for (int kt = 0; kt < 8; kt++) {
    const int kb = kt * 64;
    __syncthreads();
    #pragma unroll
    for (int p = 0; p < 8; p++) {
      int m = p * 32 + (tid >> 3), f = tid & 7;
      int c = f >> 2, qq = f & 3;
      bf16x8 v = *(const bf16x8*)(Ab + (size_t)m * H_ + kb + c * 32 + qq * 8);
      int mt = m >> 4, ld = qq * 16 + (m & 15);
      *(bf16x8*)&As[((c * 16 + mt) * 64 + ld) * 8] = v;
    }
    {
      float col[16];
      const float* src = Bw + (size_t)(kb + kg * 16) * V_ + n0 + nB;
      #pragma unroll
      for (int i = 0; i < 16; i++) col[i] = nOK ? src[(size_t)i * V_] : 0.f;
      uint4 f0, f1;
      f0.x = cvtpk(col[0],  col[1]);  f0.y = cvtpk(col[2],  col[3]);
      f0.z = cvtpk(col[4],  col[5]);  f0.w = cvtpk(col[6],  col[7]);
      f1.x = cvtpk(col[8],  col[9]);  f1.y = cvtpk(col[10], col[11]);
      f1.z = cvtpk(col[12], col[13]); f1.w = cvtpk(col[14], col[15]);
      int ld0 = q0 * 16 + (nB & 15);
      *(uint4*)&Bs[((cB * 4 + tjB) * 64 + ld0) * 8] = f0;
      *(uint4*)&Bs[((cB * 4 + tjB) * 64 + ld0 + 16) * 8] = f1;
    }
    __syncthreads();
    #pragma unroll
    for (int c = 0; c < 2; c++) {
      bf16x8 a[4], b[4];
      #pragma unroll
      for (int ti = 0; ti < 4; ti++)
        a[ti] = *(const bf16x8*)&As[((c * 16 + wv * 4 + ti) * 64 + lane) * 8];
      #pragma unroll
      for (int tj = 0; tj < 4; tj++)
        b[tj] = *(const bf16x8*)&Bs[((c * 4 + tj) * 64 + lane) * 8];
      #pragma unroll
      for (int ti = 0; ti < 4; ti++)
        #pragma unroll
        for (int tj = 0; tj < 4; tj++)
          acc[ti][tj] = __builtin_amdgcn_mfma_f32_16x16x32_bf16(a[ti], b[tj], acc[ti][tj], 0, 0, 0);
    }
  }
  #pragma unroll
  for (int ti = 0; ti < 4; ti++)
    #pragma unroll
    for (int r = 0; r < 4; r++) {
      int m = wv * 64 + ti * 16 + quad * 4 + r;
      #pragma unroll
      for (int tj = 0; tj < 4; tj++) {
        int n = n0 + tj * 16 + l15;
        if (n < V_) C[(size_t)m * V_ + n] = acc[ti][tj][r] + bias[n];
      }
    }
}

// --------------------------- small kernels ---------------------------------
__global__ __launch_bounds__(256) void attn_softmax(
    const float* __restrict__ scores, const int* __restrict__ mask, float* __restrict__ aw)
{
  int b = blockIdx.x, tid = threadIdx.x;
  __shared__ float red[256];
  float v0 = scores[b * S_ + tid];
  float v1 = scores[b * S_ + tid + 256];
  if (mask[b * S_ + tid] == 0) v0 = -1e10f;
  if (mask[b * S_ + tid + 256] == 0) v1 = -1e10f;
  red[tid] = fmaxf(v0, v1);
  __syncthreads();
  for (int off = 128; off; off >>= 1) { if (tid < off) red[tid] = fmaxf(red[tid], red[tid + off]); __syncthreads(); }
  float mx = red[0];
  __syncthreads();
  float e0 = __expf(v0 - mx), e1 = __expf(v1 - mx);
  red[tid] = e0 + e1;
  __syncthreads();
  for (int off = 128; off; off >>= 1) { if (tid < off) red[tid] += red[tid + off]; __syncthreads(); }
  float inv = 1.f / red[0];
  aw[b * S_ + tid] = e0 * inv;
  aw[b * S_ + tid + 256] = e1 * inv;
}

// S split into 8 chunks -> 2048 blocks; deterministic partials into wpart.
__global__ __launch_bounds__(512) void attn_weighted_part(
    const float* __restrict__ aw, const float* __restrict__ enc, float* __restrict__ wpart)
{
  int b = blockIdx.x, c = blockIdx.y, h = threadIdx.x;
  __shared__ float a_s[64];
  if (h < 64) a_s[h] = aw[b * S_ + c * 64 + h];
  __syncthreads();
  const float* ep = enc + ((size_t)(c * 64) * B_ + b) * H_ + h;
  float acc = 0.f;
  #pragma unroll 8
  for (int s = 0; s < 64; s++)
    acc += a_s[s] * ep[(size_t)s * B_ * H_];
  wpart[((size_t)c * B_ + b) * H_ + h] = acc;
}

__global__ void build_x(const float* __restrict__ wpart, const int* __restrict__ ids,
                        const float* __restrict__ emb, const float* __restrict__ rate,
                        float* __restrict__ x)
{
  int i = blockIdx.x * 256 + threadIdx.x;
  if (i >= B_ * RNNIN_) return;
  int b = i / RNNIN_, j = i % RNNIN_;
  float v;
  if (j < H_) {
    size_t o = (size_t)b * H_ + j;
    const size_t st = (size_t)B_ * H_;
    v = 0.f;
    #pragma unroll
    for (int c = 0; c < 8; c++) v += wpart[o + c * st];
  }
  else if (j < H_ + E_) v = emb[(size_t)ids[b] * E_ + (j - H_)];
  else v = rate[b];
  x[i] = v;
}

__global__ void gru_gates(const float* __restrict__ gi, const float* __restrict__ gh,
                          const float* __restrict__ h0, float* __restrict__ h1,
                          unsigned short* __restrict__ h1b, float* __restrict__ h1_out)
{
  int i = blockIdx.x * 256 + threadIdx.x;  // B*H
  int b = i >> 9, j = i & (H_ - 1);
  const float* gib = gi + (size_t)b * 1536;
  const float* ghb = gh + (size_t)b * 1536;
  float r = sigmoidf(gib[j] + ghb[j]);
  float z = sigmoidf(gib[512 + j] + ghb[512 + j]);
  float n = fast_tanh(gib[1024 + j] + r * ghb[1024 + j]);
  float h = (1.f - z) * n + z * h0[i];
  h1[i] = h;
  h1b[i] = (unsigned short)f2bf(h);
  h1_out[i] = h;
}

__global__ __launch_bounds__(1024) void softmax_fused(
    float* __restrict__ lp, const float* __restrict__ cv, int* __restrict__ maxid)
{
  int b = blockIdx.x, tid = threadIdx.x;
  int wid = tid >> 6, lane = tid & 63;
  float* row = lp + (size_t)b * V_;
  const float* cvr = cv + (size_t)b * V_;
  __shared__ float redf[16];
  __shared__ float rede[16];
  __shared__ int   redi[16];

  float mx = -INFINITY;
  for (int v = tid; v < V_; v += 1024) mx = fmaxf(mx, row[v]);
  #pragma unroll
  for (int o = 1; o < 64; o <<= 1) mx = fmaxf(mx, __shfl_xor(mx, o));
  if (lane == 0) redf[wid] = mx;
  __syncthreads();
  if (tid == 0) {
    float m = redf[0];
    for (int i = 1; i < 16; i++) m = fmaxf(m, redf[i]);
    redf[0] = m;
  }
  __syncthreads();
  float M = redf[0];
  __syncthreads();

  float s = 0.f, best = -1.f;
  int bi = 0;
  for (int v = tid; v < V_; v += 1024) {
    float e = __expf(row[v] - M) * cvr[v];
    row[v] = e;
    s += e;
    if (e > best) { best = e; bi = v; }
  }
  #pragma unroll
  for (int o = 1; o < 64; o <<= 1) {
    s += __shfl_xor(s, o);
    float ob = __shfl_xor(best, o);
    int oi = __shfl_xor(bi, o);
    if (ob > best || (ob == best && oi < bi)) { best = ob; bi = oi; }
  }
  if (lane == 0) { redf[wid] = s; rede[wid] = best; redi[wid] = bi; }
  __syncthreads();
  if (tid == 0) {
    float ss = 0.f, bb = rede[0];
    int ii = redi[0];
    for (int i = 0; i < 16; i++) {
      ss += redf[i];
      if (rede[i] > bb || (rede[i] == bb && redi[i] < ii)) { bb = rede[i]; ii = redi[i]; }
    }
    redf[0] = ss;
    maxid[b] = ii;
  }
  __syncthreads();
  float inv = 1.f / redf[0];
  for (int v = tid; v < V_; v += 1024) {
    float p = row[v] * inv;
    p = fminf(fmaxf(p, 1e-6f), 1.f);
    row[v] = __logf(p);
  }
}

// Tandem GEMM with fused A-gather ([emb[maxid], h1]) and relu.
__global__ __launch_bounds__(256) void tandem_gemm(
    const int* __restrict__ maxid, const float* __restrict__ emb,
    const float* __restrict__ h1, const float* __restrict__ tan_w,
    const float* __restrict__ tan_b, float* __restrict__ rate_in)
{
  __shared__ float As[16][65];
  __shared__ float Bs[16][65];
  const int m0 = blockIdx.x * 64, n0 = blockIdx.y * 64;
  const int tid = threadIdx.x;
  const int tx = tid & 15, ty = tid >> 4;
  float acc[4][4] = {};
  for (int k0 = 0; k0 < 640; k0 += 16) {
    __syncthreads();
    #pragma unroll
    for (int i = 0; i < 4; i++) {
      int e = tid + i * 256;
      int m = e >> 4, kk = e & 15;
      int mm = m0 + m, k = k0 + kk;
      float v = (k < E_) ? emb[(size_t)maxid[mm] * E_ + k]
                         : h1[(size_t)mm * H_ + (k - E_)];
      As[kk][m] = v;
    }
    #pragma unroll
    for (int i = 0; i < 4; i++) {
      int e = tid + i * 256;
      int k = e >> 6, n = e & 63;
      Bs[k][n] = tan_w[(size_t)(k0 + k) * H_ + n0 + n];
    }
    __syncthreads();
    #pragma unroll
    for (int k = 0; k < 16; k++) {
      float a[4], b[4];
      #pragma unroll
      for (int i = 0; i < 4; i++) a[i] = As[k][ty * 4 + i];
      #pragma unroll
      for (int j = 0; j < 4; j++) b[j] = Bs[k][tx * 4 + j];
      #pragma unroll
      for (int i = 0; i < 4; i++)
        #pragma unroll
        for (int j = 0; j < 4; j++) acc[i][j] += a[i] * b[j];
    }
  }
  #pragma unroll
  for (int i = 0; i < 4; i++) {
    int m = m0 + ty * 4 + i;
    #pragma unroll
    for (int j = 0; j < 4; j++) {
      int n = n0 + tx * 4 + j;
      rate_in[(size_t)m * H_ + n] = fmaxf(acc[i][j] + tan_b[n], 0.f);
    }
  }
}

__global__ __launch_bounds__(64) void rate_head(const float* __restrict__ rate_in,
                                                const float* __restrict__ rate_w,
                                                const float* __restrict__ rate_b,
                                                float* __restrict__ out)
{
  int b = blockIdx.x, t = threadIdx.x;
  float s = 0.f;
  #pragma unroll
  for (int i = 0; i < 8; i++) s += rate_in[b * H_ + t + 64 * i] * rate_w[t + 64 * i];
  #pragma unroll
  for (int m = 32; m; m >>= 1) s += __shfl_xor(s, m);
  if (t == 0) out[b] = sigmoidf(s + rate_b[0]);
}

// ---------------------------------------------------------------------------
extern "C" void kernel_launch(void* const* d_in, const int* in_sizes, int n_in,
                              void* d_out, int out_size, void* d_ws, size_t ws_size,
                              hipStream_t stream)
{
  const int*   input_id   = (const int*)  d_in[0];
  const float* input_rate = (const float*)d_in[1];
  const float* hidden     = (const float*)d_in[2];
  const float* enc        = (const float*)d_in[3];
  const int*   attn_mask  = (const int*)  d_in[4];
  const float* cv         = (const float*)d_in[5];
  const float* emb        = (const float*)d_in[6];
  const float* attn_w     = (const float*)d_in[7];
  const float* attn_b     = (const float*)d_in[8];
  const float* v_w        = (const float*)d_in[9];
  const float* w_ih       = (const float*)d_in[10];
  const float* w_hh       = (const float*)d_in[11];
  const float* b_ih       = (const float*)d_in[12];
  const float* b_hh       = (const float*)d_in[13];
  const float* fc_w       = (const float*)d_in[14];
  const float* fc_b       = (const float*)d_in[15];
  const float* tan_w      = (const float*)d_in[16];
  const float* tan_b      = (const float*)d_in[17];
  const float* rate_w     = (const float*)d_in[18];
  const float* rate_b     = (const float*)d_in[19];

  float* out = (float*)d_out;
  float* ws  = (float*)d_ws;
  float* hid_pb   = ws;                   // [0,       131072)
  float* scores   = ws + 131072;          // [131072,  262144)
  float* aw       = ws + 262144;          // [262144,  393216)
  float* xbuf     = ws + 524288;          // [524288,  688384)  B*641
  float* gi       = ws + 688384;          // [688384, 1081600)  B*1536
  float* gh       = ws + 1081600;         // [1081600,1474816)  B*1536
  float* h1       = ws + 1474816;         // [1474816,1605888)  B*H
  float* rate_in  = ws + 1605888;         // [1605888,1736960)  B*H
  int*   maxid    = (int*)(ws + 1736960); // [1736960,1737216)  B ints
  unsigned short* Btf = (unsigned short*)(ws + 1737216); // 512KB packed B
  unsigned short* h1b = (unsigned short*)(ws + 1868288); // 256*512 bf16
  // wpart: 8*B*H floats overlays [gi .. rate_in end); consumed by build_x
  // BEFORE gemm_gru/gru_gates/tandem write that region.
  float* wpart = gi;

  float* out_pred = out;
  float* out_rate = out + (size_t)B_ * V_;
  float* out_h1   = out + (size_t)B_ * V_ + B_;

  prep_fused<<<1056, 256, 0, stream>>>(attn_w, Btf, hidden, attn_b, hid_pb);

  attn_gemm_score<<<2048, 512, 0, stream>>>(enc, Btf, hid_pb, v_w, scores);

  attn_softmax<<<B_, 256, 0, stream>>>(scores, attn_mask, aw);
  attn_weighted_part<<<dim3(B_, 8), 512, 0, stream>>>(aw, enc, wpart);
  build_x<<<641, 256, 0, stream>>>(wpart, input_id, emb, input_rate, xbuf);

  gemm_gru<<<dim3(4, 24, 2), 256, 0, stream>>>(xbuf, w_ih, b_ih, gi, hidden, w_hh, b_hh, gh);
  gru_gates<<<512, 256, 0, stream>>>(gi, gh, hidden, h1, h1b, out_h1);

  logits_gemm<<<469, 256, 0, stream>>>(h1b, fc_w, fc_b, out_pred);
  softmax_fused<<<B_, 1024, 0, stream>>>(out_pred, cv, maxid);

  tandem_gemm<<<dim3(4, 8), 256, 0, stream>>>(maxid, emb, h1, tan_w, tan_b, rate_in);
  rate_head<<<B_, 64, 0, stream>>>(rate_in, rate_w, rate_b, out_rate);
}